// Round 3
// baseline (229.832 us; speedup 1.0000x reference)
//
#include <hip/hip_runtime.h>

// CASREL loss. B=32,S=512,H=1024,R=64 -> scalar fp32 loss.
// R3: TLP-based latency hiding. main grid = 2048 blocks (8/CU, 32 waves/CU
// = 100% occupancy, __launch_bounds__(256,8)). Each block: 16 rows x 80 cols;
// 4 waves split K (256 each), LDS reduction, BCE epilogue on wave 0.
// B pre-swizzled to Wt3[k/32][col][32] bf16 -> 1KB fully-coalesced fragment
// loads with immediate offsets. 2 dispatches total (ticket-based finalize).

#define B_  32
#define S_  512
#define H_  1024
#define R_  64
#define M_  (B_ * S_)      // 16384 rows
#define NPAD 160           // 130 valid cols padded to 10*16
#define NVALID 130
#define NBLK (M_ / 16 * 2) // 2048 main blocks

typedef __attribute__((ext_vector_type(4))) float  floatx4;
typedef __attribute__((ext_vector_type(8))) short  short8;     // 8 bf16

__device__ __forceinline__ unsigned short f2bf(float f) {
    unsigned int u = __float_as_uint(f);
    u = (u + 0x7FFFu + ((u >> 16) & 1u)) >> 16;   // RNE
    return (unsigned short)u;
}

// ---- K1 (fused): blocks 0..159: transpose/pad weights into swizzled
//      Wt3[k/32][160][32] bf16; blocks 160..191: per-batch rowBias;
//      block 0 also zeroes accum + ticket ----
__global__ __launch_bounds__(256) void prep_kernel(
        const float* __restrict__ ctx,  const float* __restrict__ head,
        const float* __restrict__ tail,
        const float* __restrict__ Ws_h, const float* __restrict__ Ws_t,
        const float* __restrict__ Wo_h, const float* __restrict__ Wo_t,
        const float* __restrict__ bo_h, const float* __restrict__ bo_t,
        const float* __restrict__ bs_h, const float* __restrict__ bs_t,
        unsigned short* __restrict__ Wt3, float* __restrict__ rowBias,
        float* __restrict__ accum, int* __restrict__ ticket) {
    const int blk = blockIdx.x, tid = threadIdx.x;
    if (blk == 0) {
        if (tid < 2) accum[tid] = 0.0f;
        if (tid == 2) *ticket = 0;
    }
    if (blk < NPAD) {
        const int n = blk;
        for (int k = tid; k < H_; k += 256) {
            float v;
            if (n < 64)        v = Wo_h[k * R_ + n];
            else if (n < 128)  v = Wo_t[k * R_ + (n - 64)];
            else if (n == 128) v = Ws_h[k];
            else if (n == 129) v = Ws_t[k];
            else               v = 0.0f;
            Wt3[(k >> 5) * (NPAD * 32) + n * 32 + (k & 31)] = f2bf(v);
        }
        return;
    }
    // ---- subject path, b = blk - 160 ----
    const int b = blk - NPAD;
    __shared__ float subj[H_];
    __shared__ float part[256];
    __shared__ int cnt;
    __shared__ int   sidx[4];
    __shared__ float sw[4];
    if (tid == 0) cnt = 0;
    __syncthreads();
    for (int s = tid; s < S_; s += 256) {
        float w = 0.5f * (head[b * S_ + s] + tail[b * S_ + s]);
        if (w != 0.0f) {
            int i = atomicAdd(&cnt, 1);
            if (i < 4) { sidx[i] = s; sw[i] = w; }
        }
    }
    __syncthreads();
    const int nnz = cnt < 4 ? cnt : 4;
    for (int h = tid; h < H_; h += 256) {
        float a = 0.0f;
        for (int i = 0; i < nnz; i++)
            a += sw[i] * ctx[((size_t)b * S_ + sidx[i]) * H_ + h];
        subj[h] = a;
    }
    __syncthreads();
    // GEMV subj[1024] @ W[1024][128]: tid = hf*128 + c, coalesced W reads
    {
        const int c = tid & 127, hf = tid >> 7;
        const float* W = (c < 64) ? (Wo_h + c) : (Wo_t + (c - 64));
        float a = 0.0f;
        const int k0 = hf * 512;
#pragma unroll 16
        for (int k = k0; k < k0 + 512; k++)
            a += subj[k] * W[(size_t)k * R_];
        part[tid] = a;
    }
    __syncthreads();
    if (tid < NPAD) {
        float v;
        if (tid < 128)
            v = part[tid] + part[128 + tid] + (tid < 64 ? bo_h[tid] : bo_t[tid - 64]);
        else if (tid == 128) v = bs_h[0];
        else if (tid == 129) v = bs_t[0];
        else                 v = 0.0f;
        rowBias[b * NPAD + tid] = v;
    }
}

// ---- K2: GEMM + BCE + reduction + ticket-finalize ----
__global__ __launch_bounds__(256, 8) void main_kernel(
        const float* __restrict__ ctx, const unsigned short* __restrict__ Wt3,
        const float* __restrict__ rowBias, const float* __restrict__ masks,
        const float* __restrict__ ash, const float* __restrict__ ast,
        const float* __restrict__ oh, const float* __restrict__ ot,
        float* __restrict__ accum, int* __restrict__ ticket,
        float* __restrict__ out) {
    __shared__ float red[3][64][21];   // +1 pad word per lane-slot
    const int tid  = threadIdx.x;
    const int wave = tid >> 6, lane = tid & 63;
    const int lr = lane & 15, q = lane >> 4;
    const int wn  = blockIdx.x & 1;            // col half (80 cols)
    const int gm0 = (blockIdx.x >> 1) << 4;    // 16 rows per block
    const int b   = gm0 >> 9;
    const int k0  = wave << 8;                 // K-quarter per wave

    const float* aP = ctx + (size_t)(gm0 + lr) * H_ + k0 + q * 8;
    const unsigned short* bP = Wt3 + (size_t)(k0 >> 5) * (NPAD * 32)
                               + (wn * 80 + 32 + lr) * 32 + q * 8;  // t=2 center

    floatx4 acc[5];
#pragma unroll
    for (int t = 0; t < 5; t++) acc[t] = (floatx4){0.f, 0.f, 0.f, 0.f};

#pragma unroll
    for (int it = 0; it < 8; ++it) {
        const float4 a0 = *(const float4*)(aP + it * 32);
        const float4 a1 = *(const float4*)(aP + it * 32 + 4);
        short8 bv[5];
#pragma unroll
        for (int t = 0; t < 5; t++)
            bv[t] = *(const short8*)(bP + (t - 2) * 512);   // +-1KB imm offsets
        bP += NPAD * 32;
        short8 af;
        af[0] = (short)f2bf(a0.x); af[1] = (short)f2bf(a0.y);
        af[2] = (short)f2bf(a0.z); af[3] = (short)f2bf(a0.w);
        af[4] = (short)f2bf(a1.x); af[5] = (short)f2bf(a1.y);
        af[6] = (short)f2bf(a1.z); af[7] = (short)f2bf(a1.w);
#pragma unroll
        for (int t = 0; t < 5; t++)
            acc[t] = __builtin_amdgcn_mfma_f32_16x16x32_bf16(af, bv[t], acc[t], 0, 0, 0);
    }

    if (wave != 0) {
#pragma unroll
        for (int t = 0; t < 5; t++)
#pragma unroll
            for (int i = 0; i < 4; i++)
                red[wave - 1][lane][t * 4 + i] = acc[t][i];
    }
    // mask partial sum: one wave of the wn==0 block per row-set
    if (wn == 0 && wave == 1 && lane < 16) {
        float mv = masks[gm0 + lane];
#pragma unroll
        for (int o = 8; o > 0; o >>= 1) mv += __shfl_down(mv, o, 64);
        if (lane == 0) atomicAdd(&accum[1], mv);
    }
    __syncthreads();
    if (wave == 0) {
        float lsum = 0.0f;
#pragma unroll
        for (int t = 0; t < 5; t++) {
            const int col = wn * 80 + t * 16 + lr;
#pragma unroll
            for (int i = 0; i < 4; i++) {
                const float v = acc[t][i] + red[0][lane][t * 4 + i]
                              + red[1][lane][t * 4 + i] + red[2][lane][t * 4 + i];
                if (col < NVALID) {
                    const int row = gm0 + q * 4 + i;
                    const float l = v + rowBias[b * NPAD + col];
                    float tgt;
                    if (col < 64)        tgt = oh[row * R_ + col];
                    else if (col < 128)  tgt = ot[row * R_ + (col - 64)];
                    else if (col == 128) tgt = ash[row];
                    else                 tgt = ast[row];
                    const float bce = fmaxf(l, 0.0f) - l * tgt
                                    + log1pf(__expf(-fabsf(l)));
                    lsum += bce * masks[row];
                }
            }
        }
#pragma unroll
        for (int o = 32; o > 0; o >>= 1) lsum += __shfl_down(lsum, o, 64);
        if (lane == 0) atomicAdd(&accum[0], lsum);
    }
    __syncthreads();
    if (tid == 0) {
        __threadfence();
        const int old = atomicAdd(ticket, 1);
        if (old == NBLK - 1) {
            const float s = atomicAdd(&accum[0], 0.0f);   // coherent read
            const float m = atomicAdd(&accum[1], 0.0f);
            out[0] = s / m;
        }
    }
}

extern "C" void kernel_launch(void* const* d_in, const int* in_sizes, int n_in,
                              void* d_out, int out_size, void* d_ws, size_t ws_size,
                              hipStream_t stream) {
    const float* ctx   = (const float*)d_in[0];
    const float* masks = (const float*)d_in[1];
    const float* ash   = (const float*)d_in[2];
    const float* ast   = (const float*)d_in[3];
    const float* sh    = (const float*)d_in[4];
    const float* st    = (const float*)d_in[5];
    const float* oh    = (const float*)d_in[6];
    const float* ot    = (const float*)d_in[7];
    const float* Ws_h  = (const float*)d_in[8];
    const float* bs_h  = (const float*)d_in[9];
    const float* Ws_t  = (const float*)d_in[10];
    const float* bs_t  = (const float*)d_in[11];
    const float* Wo_h  = (const float*)d_in[12];
    const float* bo_h  = (const float*)d_in[13];
    const float* Wo_t  = (const float*)d_in[14];
    const float* bo_t  = (const float*)d_in[15];
    float* out = (float*)d_out;

    char* ws = (char*)d_ws;
    float* accum   = (float*)(ws + 0);          // [0]=loss sum, [1]=mask sum
    int*   ticket  = (int*)(ws + 64);
    float* rowBias = (float*)(ws + 256);        // [32][160] fp32
    unsigned short* Wt3 = (unsigned short*)(ws + 256 + 32 * NPAD * 4); // [32][160][32] bf16

    prep_kernel<<<NPAD + B_, 256, 0, stream>>>(ctx, sh, st, Ws_h, Ws_t,
                                               Wo_h, Wo_t, bo_h, bo_t, bs_h, bs_t,
                                               Wt3, rowBias, accum, ticket);
    main_kernel<<<NBLK, 256, 0, stream>>>(ctx, Wt3, rowBias, masks,
                                          ash, ast, oh, ot, accum, ticket, out);
}